// Round 3
// baseline (6203.873 us; speedup 1.0000x reference)
//
#include <hip/hip_runtime.h>

#define Bx 64
#define Tx 512
#define Dx 1024
#define Ux 1024
#define Mx (Bx*Tx)   // 32768

typedef __attribute__((ext_vector_type(8))) short short8;
typedef __attribute__((ext_vector_type(4))) float f32x4;

static __device__ __forceinline__ unsigned short f2bf(float f){
  unsigned int u = __builtin_bit_cast(unsigned int, f);
  u = (u + 0x7FFFu + ((u >> 16) & 1u)) >> 16;
  return (unsigned short)u;
}
static __device__ __forceinline__ float bf2f(unsigned short s){
  unsigned int u = ((unsigned int)s) << 16;
  return __builtin_bit_cast(float, u);
}

// ---------------------------------------------------------------------------
// prep: W1T[n][k] = bf16(W1[k][n]); W2T[n][k] = bf16(W2[k][n])  (1024x1024)
// ---------------------------------------------------------------------------
__global__ __launch_bounds__(256) void prep_kernel(
    const float* __restrict__ W1, const float* __restrict__ W2,
    unsigned short* __restrict__ W1T, unsigned short* __restrict__ W2T)
{
  __shared__ unsigned short tile[64][72];
  const float* src = blockIdx.y ? W2 : W1;
  unsigned short* dst = blockIdx.y ? W2T : W1T;
  const int bi = blockIdx.x >> 4;
  const int bj = blockIdx.x & 15;
  const int r  = threadIdx.x >> 2;
  const int c0 = (threadIdx.x & 3) * 16;
  for (int i = 0; i < 4; ++i){
    float4 v = *(const float4*)&src[(size_t)(bi*64 + r)*1024 + bj*64 + c0 + i*4];
    tile[r][c0+i*4+0] = f2bf(v.x);
    tile[r][c0+i*4+1] = f2bf(v.y);
    tile[r][c0+i*4+2] = f2bf(v.z);
    tile[r][c0+i*4+3] = f2bf(v.w);
  }
  __syncthreads();
  unsigned short tmp[16];
  #pragma unroll
  for (int i = 0; i < 16; ++i) tmp[i] = tile[c0+i][r];
  unsigned int w[8];
  #pragma unroll
  for (int i = 0; i < 8; ++i) w[i] = (unsigned int)tmp[2*i] | ((unsigned int)tmp[2*i+1] << 16);
  unsigned short* o = &dst[(size_t)(bj*64 + r)*1024 + bi*64 + c0];
  *(uint4*)o       = make_uint4(w[0],w[1],w[2],w[3]);
  *(uint4*)(o + 8) = make_uint4(w[4],w[5],w[6],w[7]);
}

// ---------------------------------------------------------------------------
// gemm_h: h[m][n] = tanh( X[m][:] @ W1[:][n] + b1[n] ), fp32 out. (unchanged)
// ---------------------------------------------------------------------------
__global__ __launch_bounds__(256) void gemm_h(
    const float* __restrict__ X, const unsigned short* __restrict__ W1T,
    const float* __restrict__ b1, float* __restrict__ h)
{
  __shared__ unsigned short Ah[128][40];
  __shared__ unsigned short Al[128][40];
  __shared__ unsigned short Bt[128][40];
  const int m0 = blockIdx.x * 128, n0 = blockIdx.y * 128;
  const int tid = threadIdx.x;
  const int lane = tid & 63, wave = tid >> 6;
  const int mq = (wave >> 1) * 64, nq = (wave & 1) * 64;
  const int rs = tid >> 1, ks = (tid & 1) * 16;
  f32x4 z = {0.f, 0.f, 0.f, 0.f};
  f32x4 acc[4][4];
  for (int i = 0; i < 4; ++i) for (int j = 0; j < 4; ++j) acc[i][j] = z;

  const int mm = lane & 15, g = lane >> 4;
  for (int kc = 0; kc < 32; ++kc){
    const int kg = kc * 32;
    {
      const float* xp = &X[(size_t)(m0 + rs)*1024 + kg + ks];
      #pragma unroll
      for (int i = 0; i < 4; ++i){
        float4 v = *(const float4*)(xp + i*4);
        unsigned short h0=f2bf(v.x), h1=f2bf(v.y), h2=f2bf(v.z), h3=f2bf(v.w);
        unsigned short l0=f2bf(v.x-bf2f(h0)), l1=f2bf(v.y-bf2f(h1));
        unsigned short l2=f2bf(v.z-bf2f(h2)), l3=f2bf(v.w-bf2f(h3));
        *(uint2*)&Ah[rs][ks+i*4] = make_uint2((unsigned)h0|((unsigned)h1<<16), (unsigned)h2|((unsigned)h3<<16));
        *(uint2*)&Al[rs][ks+i*4] = make_uint2((unsigned)l0|((unsigned)l1<<16), (unsigned)l2|((unsigned)l3<<16));
      }
      const unsigned short* wp = &W1T[(size_t)(n0 + rs)*1024 + kg + ks];
      *(uint4*)&Bt[rs][ks]     = *(const uint4*)wp;
      *(uint4*)&Bt[rs][ks + 8] = *(const uint4*)(wp + 8);
    }
    __syncthreads();
    short8 bf[4], ah[4], al[4];
    #pragma unroll
    for (int j = 0; j < 4; ++j) bf[j] = *(const short8*)&Bt[nq + j*16 + mm][g*8];
    #pragma unroll
    for (int i = 0; i < 4; ++i){
      ah[i] = *(const short8*)&Ah[mq + i*16 + mm][g*8];
      al[i] = *(const short8*)&Al[mq + i*16 + mm][g*8];
    }
    #pragma unroll
    for (int i = 0; i < 4; ++i)
      #pragma unroll
      for (int j = 0; j < 4; ++j){
        acc[i][j] = __builtin_amdgcn_mfma_f32_16x16x32_bf16(ah[i], bf[j], acc[i][j], 0, 0, 0);
        acc[i][j] = __builtin_amdgcn_mfma_f32_16x16x32_bf16(al[i], bf[j], acc[i][j], 0, 0, 0);
      }
    __syncthreads();
  }
  for (int i = 0; i < 4; ++i){
    const int mbase = m0 + mq + i*16 + g*4;
    for (int j = 0; j < 4; ++j){
      const int n = n0 + nq + j*16 + mm;
      const float bias = b1[n];
      #pragma unroll
      for (int r = 0; r < 4; ++r)
        h[(size_t)(mbase + r)*1024 + n] = tanhf(acc[i][j][r] + bias);
    }
  }
}

// ---------------------------------------------------------------------------
// rnn_scan v3: wave-independent exchange.
//  - state as separate hi/lo bf16 planes; A-frags loaded DIRECTLY from global
//    via 8B relaxed agent atomic loads (bypass L2 -> MALL), no LDS staging.
//  - per-producer-WAVE flags (64/group/step); publish = relaxed data stores +
//    s_waitcnt vmcnt(0) + relaxed flag store (no RELEASE -> no wbl2).
//  - zero __syncthreads in the 512-step loop; feat stores after flag publish.
// 256 WGs = 32 col-parts x 8 batch-groups, 128 threads (2 independent waves).
// ---------------------------------------------------------------------------
__global__ __launch_bounds__(128) void rnn_scan(
    const unsigned short* __restrict__ W2T, const float* __restrict__ hbuf,
    const float* __restrict__ b2,
    unsigned short* sH0, unsigned short* sL0,
    unsigned short* sH1, unsigned short* sL1,
    unsigned int* flags, unsigned short* __restrict__ feat)
{
  __shared__ unsigned short Wt[32][1024];   // 64 KB, XOR-swizzled, read-only
  const int wg = blockIdx.x;
  const int p = wg & 31, q = wg >> 5;
  const int n0 = p * 32, b0 = q * 8;
  const int tid = threadIdx.x, lane = tid & 63, wv = tid >> 6;

  // load W2T slice [n0..n0+32)[0..1024) with chunk-XOR swizzle
  for (int i = 0; i < 32; ++i){
    int f = i * 128 + tid;
    int nn = f >> 7, c = f & 127;
    uint4 v = *(const uint4*)&W2T[(size_t)(n0 + nn)*1024 + c*8];
    int cs = c ^ (nn & 7);
    *(uint4*)&Wt[nn][cs*8] = v;
  }
  __syncthreads();   // only barrier; Wt is read-only afterwards

  const int mm = lane & 15, g = lane >> 4;
  const int r8 = mm & 7;
  const int nloc = wv*16 + mm;
  const int wid = p*2 + wv;                  // producer-wave id in group (0..63)
  const int n = n0 + nloc;                   // this lane's output col
  const size_t arow = (size_t)(b0 + r8) * 1024;
  const bool act = (g < 2);
  const int brow = b0 + g*4;                 // epilogue base row (valid if act)
  unsigned int* gflag = flags + (size_t)q * 512 * 64;
  const float bias = b2[n];

  #pragma unroll 1
  for (int t = 0; t < 512; ++t){
    const unsigned short* rH = (t & 1) ? sH1 : sH0;
    const unsigned short* rL = (t & 1) ? sL1 : sL0;
    unsigned short* wH = (t & 1) ? sH0 : sH1;
    unsigned short* wL = (t & 1) ? sL0 : sL1;

    // prefetch hbuf[t] before the poll (hides HBM latency behind the wait)
    float hv[4];
    if (act){
      #pragma unroll
      for (int r = 0; r < 4; ++r)
        hv[r] = hbuf[(size_t)(brow + r)*Tx*Ux + (size_t)t*Ux + n];
    }

    // wait for all 64 producer waves of step t-1 (one flag word per lane)
    if (t > 0){
      const unsigned int* f = gflag + (size_t)(t-1)*64 + lane;
      while (true){
        unsigned int v = __hip_atomic_load(f, __ATOMIC_RELAXED, __HIP_MEMORY_SCOPE_AGENT);
        if (__all(v != 0)) break;
        __builtin_amdgcn_s_sleep(1);
      }
    }

    // A-frags straight from global (bypass loads), B-frags from LDS
    f32x4 a0 = {0,0,0,0}, a1 = {0,0,0,0}, a2 = {0,0,0,0}, a3 = {0,0,0,0};
    #pragma unroll 4
    for (int ks = 0; ks < 16; ++ks){
      const int k0 = ks * 64;
      const unsigned short* ph = rH + arow + k0 + g*8;
      const unsigned short* pl = rL + arow + k0 + g*8;
      union { unsigned long long qw[2]; short8 s; } uh0, ul0, uh1, ul1;
      uh0.qw[0] = __hip_atomic_load((const unsigned long long*)(ph),    __ATOMIC_RELAXED, __HIP_MEMORY_SCOPE_AGENT);
      uh0.qw[1] = __hip_atomic_load((const unsigned long long*)(ph+4),  __ATOMIC_RELAXED, __HIP_MEMORY_SCOPE_AGENT);
      ul0.qw[0] = __hip_atomic_load((const unsigned long long*)(pl),    __ATOMIC_RELAXED, __HIP_MEMORY_SCOPE_AGENT);
      ul0.qw[1] = __hip_atomic_load((const unsigned long long*)(pl+4),  __ATOMIC_RELAXED, __HIP_MEMORY_SCOPE_AGENT);
      uh1.qw[0] = __hip_atomic_load((const unsigned long long*)(ph+32), __ATOMIC_RELAXED, __HIP_MEMORY_SCOPE_AGENT);
      uh1.qw[1] = __hip_atomic_load((const unsigned long long*)(ph+36), __ATOMIC_RELAXED, __HIP_MEMORY_SCOPE_AGENT);
      ul1.qw[0] = __hip_atomic_load((const unsigned long long*)(pl+32), __ATOMIC_RELAXED, __HIP_MEMORY_SCOPE_AGENT);
      ul1.qw[1] = __hip_atomic_load((const unsigned long long*)(pl+36), __ATOMIC_RELAXED, __HIP_MEMORY_SCOPE_AGENT);
      const int c0 = ks*8 + g, c1 = c0 + 4;
      short8 b0f = *(const short8*)&Wt[nloc][(c0 ^ (nloc & 7))*8];
      short8 b1f = *(const short8*)&Wt[nloc][(c1 ^ (nloc & 7))*8];
      a0 = __builtin_amdgcn_mfma_f32_16x16x32_bf16(uh0.s, b0f, a0, 0,0,0);
      a1 = __builtin_amdgcn_mfma_f32_16x16x32_bf16(ul0.s, b0f, a1, 0,0,0);
      a2 = __builtin_amdgcn_mfma_f32_16x16x32_bf16(uh1.s, b1f, a2, 0,0,0);
      a3 = __builtin_amdgcn_mfma_f32_16x16x32_bf16(ul1.s, b1f, a3, 0,0,0);
    }
    f32x4 acc = (a0 + a1) + (a2 + a3);

    // epilogue: lanes g<2 hold rows brow..brow+3, col = n. Pack col pairs.
    unsigned int dwh[4], dwl[4];
    if (act){
      #pragma unroll
      for (int r = 0; r < 4; ++r){
        const float y = hv[r] + tanhf(acc[r] + bias);
        unsigned short yh = f2bf(y);
        unsigned short yl = f2bf(y - bf2f(yh));
        unsigned int oh = __shfl_xor((unsigned int)yh, 1);
        unsigned int ol = __shfl_xor((unsigned int)yl, 1);
        dwh[r] = (unsigned int)yh | (oh << 16);
        dwl[r] = (unsigned int)yl | (ol << 16);
      }
      if (!(mm & 1)){
        #pragma unroll
        for (int r = 0; r < 4; ++r){
          __hip_atomic_store((unsigned int*)(wH + (size_t)(brow + r)*1024 + n), dwh[r],
                             __ATOMIC_RELAXED, __HIP_MEMORY_SCOPE_AGENT);
          __hip_atomic_store((unsigned int*)(wL + (size_t)(brow + r)*1024 + n), dwl[r],
                             __ATOMIC_RELAXED, __HIP_MEMORY_SCOPE_AGENT);
        }
      }
    }
    // hand-rolled release: drain this wave's vmem (state stores are at the
    // coherence point), then fire-and-forget the flag. No wbl2, no barrier.
    asm volatile("s_waitcnt vmcnt(0)" ::: "memory");
    if (lane == 0)
      __hip_atomic_store(gflag + (size_t)t*64 + wid, 1u,
                         __ATOMIC_RELAXED, __HIP_MEMORY_SCOPE_AGENT);
    // feat stores AFTER publish: off the critical path
    if (act && !(mm & 1)){
      #pragma unroll
      for (int r = 0; r < 4; ++r)
        *(unsigned int*)(feat + (size_t)(brow + r)*Tx*Ux + (size_t)t*Ux + n) = dwh[r];
    }
  }
}

// ---------------------------------------------------------------------------
// proj_out: out[m] = feat[m][:] (bf16) . Wc (fp32) + bc
// ---------------------------------------------------------------------------
__global__ __launch_bounds__(256) void proj_out(
    const unsigned short* __restrict__ feat, const float* __restrict__ Wc,
    const float* __restrict__ bc, float* __restrict__ out)
{
  const int wv = threadIdx.x >> 6, lane = threadIdx.x & 63;
  const int m = blockIdx.x * 4 + wv;
  const unsigned short* fp = &feat[(size_t)m*1024 + lane*16];
  float s = 0.f;
  #pragma unroll
  for (int i = 0; i < 2; ++i){
    uint4 v = *(const uint4*)(fp + i*8);
    float4 w0 = *(const float4*)&Wc[lane*16 + i*8];
    float4 w1 = *(const float4*)&Wc[lane*16 + i*8 + 4];
    unsigned int vv[4] = {v.x, v.y, v.z, v.w};
    s += bf2f((unsigned short)(vv[0] & 0xFFFF))*w0.x + bf2f((unsigned short)(vv[0] >> 16))*w0.y;
    s += bf2f((unsigned short)(vv[1] & 0xFFFF))*w0.z + bf2f((unsigned short)(vv[1] >> 16))*w0.w;
    s += bf2f((unsigned short)(vv[2] & 0xFFFF))*w1.x + bf2f((unsigned short)(vv[2] >> 16))*w1.y;
    s += bf2f((unsigned short)(vv[3] & 0xFFFF))*w1.z + bf2f((unsigned short)(vv[3] >> 16))*w1.w;
  }
  for (int o = 32; o; o >>= 1) s += __shfl_down(s, o);
  if (lane == 0) out[m] = s + bc[0];
}

// ---------------------------------------------------------------------------
extern "C" void kernel_launch(void* const* d_in, const int* in_sizes, int n_in,
                              void* d_out, int out_size, void* d_ws, size_t ws_size,
                              hipStream_t stream)
{
  (void)in_sizes; (void)n_in; (void)out_size; (void)ws_size;
  const float* X  = (const float*)d_in[0];
  const float* W1 = (const float*)d_in[1];
  const float* b1 = (const float*)d_in[2];
  const float* W2 = (const float*)d_in[3];
  const float* b2 = (const float*)d_in[4];
  const float* Wc = (const float*)d_in[5];
  const float* bc = (const float*)d_in[6];
  float* out = (float*)d_out;
  char* ws = (char*)d_ws;

  unsigned short* W1T  = (unsigned short*)(ws + 0);          // 2 MiB
  unsigned short* W2T  = (unsigned short*)(ws + 2097152);    // 2 MiB
  unsigned short* sH0  = (unsigned short*)(ws + 4194304);    // 128 KiB each
  unsigned short* sL0  = (unsigned short*)(ws + 4325376);
  unsigned short* sH1  = (unsigned short*)(ws + 4456448);
  unsigned short* sL1  = (unsigned short*)(ws + 4587520);
  unsigned int*   flags= (unsigned int*)  (ws + 4718592);    // 1 MiB (8*512*64*4)
  float* hbuf          = (float*)         (ws + 6291456);    // 128 MiB
  unsigned short* feat = (unsigned short*)(ws + 6291456 + 134217728); // 64 MiB

  // zero state planes + flags (contiguous 1.5 MiB)
  hipMemsetAsync(sH0, 0, 524288 + 1048576, stream);

  prep_kernel<<<dim3(256, 2), 256, 0, stream>>>(W1, W2, W1T, W2T);
  gemm_h<<<dim3(Mx/128, Ux/128), 256, 0, stream>>>(X, W1T, b1, hbuf);

  void* args[] = { (void*)&W2T, (void*)&hbuf, (void*)&b2,
                   (void*)&sH0, (void*)&sL0, (void*)&sH1, (void*)&sL1,
                   (void*)&flags, (void*)&feat };
  hipLaunchCooperativeKernel((void*)rnn_scan, dim3(256), dim3(128), args, 0, stream);

  proj_out<<<Mx/4, 256, 0, stream>>>(feat, Wc, bc, out);
}

// Round 7
// 3136.910 us; speedup vs baseline: 1.9777x; 1.9777x over previous
//
#include <hip/hip_runtime.h>

#define Bx 64
#define Tx 512
#define Dx 1024
#define Ux 1024
#define Mx (Bx*Tx)   // 32768

typedef __attribute__((ext_vector_type(8))) short short8;
typedef __attribute__((ext_vector_type(4))) float f32x4;
typedef __attribute__((ext_vector_type(4))) unsigned int u32x4;

static __device__ __forceinline__ unsigned short f2bf(float f){
  unsigned int u = __builtin_bit_cast(unsigned int, f);
  u = (u + 0x7FFFu + ((u >> 16) & 1u)) >> 16;
  return (unsigned short)u;
}
static __device__ __forceinline__ float bf2f(unsigned short s){
  unsigned int u = ((unsigned int)s) << 16;
  return __builtin_bit_cast(float, u);
}

// ---------------------------------------------------------------------------
// prep: W1T[n][k] = bf16(W1[k][n]); W2T[n][k] = bf16(W2[k][n])  (1024x1024)
// ---------------------------------------------------------------------------
__global__ __launch_bounds__(256) void prep_kernel(
    const float* __restrict__ W1, const float* __restrict__ W2,
    unsigned short* __restrict__ W1T, unsigned short* __restrict__ W2T)
{
  __shared__ unsigned short tile[64][72];
  const float* src = blockIdx.y ? W2 : W1;
  unsigned short* dst = blockIdx.y ? W2T : W1T;
  const int bi = blockIdx.x >> 4;
  const int bj = blockIdx.x & 15;
  const int r  = threadIdx.x >> 2;
  const int c0 = (threadIdx.x & 3) * 16;
  for (int i = 0; i < 4; ++i){
    float4 v = *(const float4*)&src[(size_t)(bi*64 + r)*1024 + bj*64 + c0 + i*4];
    tile[r][c0+i*4+0] = f2bf(v.x);
    tile[r][c0+i*4+1] = f2bf(v.y);
    tile[r][c0+i*4+2] = f2bf(v.z);
    tile[r][c0+i*4+3] = f2bf(v.w);
  }
  __syncthreads();
  unsigned short tmp[16];
  #pragma unroll
  for (int i = 0; i < 16; ++i) tmp[i] = tile[c0+i][r];
  unsigned int w[8];
  #pragma unroll
  for (int i = 0; i < 8; ++i) w[i] = (unsigned int)tmp[2*i] | ((unsigned int)tmp[2*i+1] << 16);
  unsigned short* o = &dst[(size_t)(bj*64 + r)*1024 + bi*64 + c0];
  *(uint4*)o       = make_uint4(w[0],w[1],w[2],w[3]);
  *(uint4*)(o + 8) = make_uint4(w[4],w[5],w[6],w[7]);
}

// ---------------------------------------------------------------------------
// gemm_h: h[m][n] = tanh( X[m][:] @ W1[:][n] + b1[n] ), fp32 out. (unchanged)
// ---------------------------------------------------------------------------
__global__ __launch_bounds__(256) void gemm_h(
    const float* __restrict__ X, const unsigned short* __restrict__ W1T,
    const float* __restrict__ b1, float* __restrict__ h)
{
  __shared__ unsigned short Ah[128][40];
  __shared__ unsigned short Al[128][40];
  __shared__ unsigned short Bt[128][40];
  const int m0 = blockIdx.x * 128, n0 = blockIdx.y * 128;
  const int tid = threadIdx.x;
  const int lane = tid & 63, wave = tid >> 6;
  const int mq = (wave >> 1) * 64, nq = (wave & 1) * 64;
  const int rs = tid >> 1, ks = (tid & 1) * 16;
  f32x4 z = {0.f, 0.f, 0.f, 0.f};
  f32x4 acc[4][4];
  for (int i = 0; i < 4; ++i) for (int j = 0; j < 4; ++j) acc[i][j] = z;

  const int mm = lane & 15, g = lane >> 4;
  for (int kc = 0; kc < 32; ++kc){
    const int kg = kc * 32;
    {
      const float* xp = &X[(size_t)(m0 + rs)*1024 + kg + ks];
      #pragma unroll
      for (int i = 0; i < 4; ++i){
        float4 v = *(const float4*)(xp + i*4);
        unsigned short h0=f2bf(v.x), h1=f2bf(v.y), h2=f2bf(v.z), h3=f2bf(v.w);
        unsigned short l0=f2bf(v.x-bf2f(h0)), l1=f2bf(v.y-bf2f(h1));
        unsigned short l2=f2bf(v.z-bf2f(h2)), l3=f2bf(v.w-bf2f(h3));
        *(uint2*)&Ah[rs][ks+i*4] = make_uint2((unsigned)h0|((unsigned)h1<<16), (unsigned)h2|((unsigned)h3<<16));
        *(uint2*)&Al[rs][ks+i*4] = make_uint2((unsigned)l0|((unsigned)l1<<16), (unsigned)l2|((unsigned)l3<<16));
      }
      const unsigned short* wp = &W1T[(size_t)(n0 + rs)*1024 + kg + ks];
      *(uint4*)&Bt[rs][ks]     = *(const uint4*)wp;
      *(uint4*)&Bt[rs][ks + 8] = *(const uint4*)(wp + 8);
    }
    __syncthreads();
    short8 bf[4], ah[4], al[4];
    #pragma unroll
    for (int j = 0; j < 4; ++j) bf[j] = *(const short8*)&Bt[nq + j*16 + mm][g*8];
    #pragma unroll
    for (int i = 0; i < 4; ++i){
      ah[i] = *(const short8*)&Ah[mq + i*16 + mm][g*8];
      al[i] = *(const short8*)&Al[mq + i*16 + mm][g*8];
    }
    #pragma unroll
    for (int i = 0; i < 4; ++i)
      #pragma unroll
      for (int j = 0; j < 4; ++j){
        acc[i][j] = __builtin_amdgcn_mfma_f32_16x16x32_bf16(ah[i], bf[j], acc[i][j], 0, 0, 0);
        acc[i][j] = __builtin_amdgcn_mfma_f32_16x16x32_bf16(al[i], bf[j], acc[i][j], 0, 0, 0);
      }
    __syncthreads();
  }
  for (int i = 0; i < 4; ++i){
    const int mbase = m0 + mq + i*16 + g*4;
    for (int j = 0; j < 4; ++j){
      const int n = n0 + nq + j*16 + mm;
      const float bias = b1[n];
      #pragma unroll
      for (int r = 0; r < 4; ++r)
        h[(size_t)(mbase + r)*1024 + n] = tanhf(acc[i][j][r] + bias);
    }
  }
}

// ---------------------------------------------------------------------------
// rnn_scan v7: proven device-scope protocol; consumer transport widened.
//  - producer: 4B relaxed agent atomic stores (state, packed hi<<16|lo),
//    vmcnt(0) drain, per-wave atomic flag (all v2/v3-proven).
//  - consumer: poll = atomic loads (proven); state staging = WG-cooperative
//    non-atomic global_load_dwordx4 sc0 sc1 (system-scope: bypass L1+L2,
//    read MALL = the same coherence point the atomics use; 16B/op,
//    line-granular -> ~8x less MALL op pressure than cracked atomics).
//  - roles from blockIdx (no census). One __syncthreads per step.
// 256 WGs = 32 col-parts x 8 batch-groups, 128 threads.
// ---------------------------------------------------------------------------
__global__ __launch_bounds__(128) void rnn_scan(
    const unsigned short* __restrict__ W2T, const float* __restrict__ hbuf,
    const float* __restrict__ b2,
    unsigned int* sP0, unsigned int* sP1,
    unsigned int* flags, unsigned short* __restrict__ feat)
{
  __shared__ unsigned short Wt[32][1024];   // 64 KB, XOR-swizzled
  __shared__ unsigned short Shi[8][1040];
  __shared__ unsigned short Slo[8][1040];
  const int tid = threadIdx.x, lane = tid & 63, wv = tid >> 6;
  const int p = (int)blockIdx.x & 31, q = (int)blockIdx.x >> 5;
  const int n0 = p * 32, b0 = q * 8;

  // ---- load W2T slice [n0..n0+32)[0..1024), chunk-XOR swizzle -------------
  for (int i = 0; i < 32; ++i){
    int f = i * 128 + tid;
    int nn = f >> 7, c = f & 127;
    uint4 v = *(const uint4*)&W2T[(size_t)(n0 + nn)*1024 + c*8];
    int cs = c ^ (nn & 7);
    *(uint4*)&Wt[nn][cs*8] = v;
  }
  __syncthreads();

  const int mm = lane & 15, g = lane >> 4;
  const int r8 = lane & 7;
  const int nloc = wv*16 + mm;
  const int wid = p*2 + wv;                 // producer-wave id in group (0..63)
  const int n = n0 + nloc;
  const bool act = (g < 2);
  const int brow = b0 + g*4;
  unsigned int* gflag = flags + (size_t)q * 512 * 64;
  const float bias = b2[n];

  #pragma unroll 1
  for (int t = 0; t < 512; ++t){
    const unsigned int* rsg = (t & 1) ? sP1 : sP0;
    unsigned int* wsb = (t & 1) ? sP0 : sP1;

    // prefetch hbuf[t] before the poll
    float hv[4];
    if (act){
      #pragma unroll
      for (int r = 0; r < 4; ++r)
        hv[r] = hbuf[(size_t)(brow + r)*Tx*Ux + (size_t)t*Ux + n];
    }

    // ---- wait for all 64 producer waves of step t-1 (proven atomic poll) --
    if (t > 0){
      const unsigned int* f = gflag + (size_t)(t-1)*64 + lane;
      int budget = 1 << 22;
      while (true){
        unsigned int v = __hip_atomic_load(f, __ATOMIC_RELAXED, __HIP_MEMORY_SCOPE_AGENT);
        if (__all(v != 0) || --budget == 0) break;
        __builtin_amdgcn_s_sleep(1);
      }
    }

    // ---- stage state slice (8 rows x 1024 packed dwords = 32 KB/WG) -------
    // WG-cooperative, non-atomic dwordx4 system-scope (sc0 sc1) loads.
    const unsigned int* sp = rsg + (size_t)b0 * 1024;
    u32x4 dd[16];
    {
      const unsigned int base = (unsigned int)tid * 16u;
      u32x4 d0,d1,d2,d3,d4,d5,d6,d7;
      asm volatile(
        "global_load_dwordx4 %0, %8,  %16 sc0 sc1\n\t"
        "global_load_dwordx4 %1, %9,  %16 sc0 sc1\n\t"
        "global_load_dwordx4 %2, %10, %16 sc0 sc1\n\t"
        "global_load_dwordx4 %3, %11, %16 sc0 sc1\n\t"
        "global_load_dwordx4 %4, %12, %16 sc0 sc1\n\t"
        "global_load_dwordx4 %5, %13, %16 sc0 sc1\n\t"
        "global_load_dwordx4 %6, %14, %16 sc0 sc1\n\t"
        "global_load_dwordx4 %7, %15, %16 sc0 sc1\n\t"
        "s_waitcnt vmcnt(0)"
        : "=&v"(d0),"=&v"(d1),"=&v"(d2),"=&v"(d3),
          "=&v"(d4),"=&v"(d5),"=&v"(d6),"=&v"(d7)
        : "v"(base),        "v"(base+ 2048u), "v"(base+ 4096u), "v"(base+ 6144u),
          "v"(base+ 8192u), "v"(base+10240u), "v"(base+12288u), "v"(base+14336u),
          "s"(sp)
        : "memory");
      dd[0]=d0; dd[1]=d1; dd[2]=d2; dd[3]=d3; dd[4]=d4; dd[5]=d5; dd[6]=d6; dd[7]=d7;
      asm volatile(
        "global_load_dwordx4 %0, %8,  %16 sc0 sc1\n\t"
        "global_load_dwordx4 %1, %9,  %16 sc0 sc1\n\t"
        "global_load_dwordx4 %2, %10, %16 sc0 sc1\n\t"
        "global_load_dwordx4 %3, %11, %16 sc0 sc1\n\t"
        "global_load_dwordx4 %4, %12, %16 sc0 sc1\n\t"
        "global_load_dwordx4 %5, %13, %16 sc0 sc1\n\t"
        "global_load_dwordx4 %6, %14, %16 sc0 sc1\n\t"
        "global_load_dwordx4 %7, %15, %16 sc0 sc1\n\t"
        "s_waitcnt vmcnt(0)"
        : "=&v"(d0),"=&v"(d1),"=&v"(d2),"=&v"(d3),
          "=&v"(d4),"=&v"(d5),"=&v"(d6),"=&v"(d7)
        : "v"(base+16384u), "v"(base+18432u), "v"(base+20480u), "v"(base+22528u),
          "v"(base+24576u), "v"(base+26624u), "v"(base+28672u), "v"(base+30720u),
          "s"(sp)
        : "memory");
      dd[8]=d0; dd[9]=d1; dd[10]=d2; dd[11]=d3; dd[12]=d4; dd[13]=d5; dd[14]=d6; dd[15]=d7;
    }
    // unpack packed dwords -> LDS hi/lo planes
    #pragma unroll
    for (int i = 0; i < 16; ++i){
      const int c = tid + 128*i;
      const int row = c >> 8, col = (c & 255) * 4;
      u32x4 d = dd[i];
      unsigned int h0 = (d.x >> 16) | (d.y & 0xffff0000u);
      unsigned int h1 = (d.z >> 16) | (d.w & 0xffff0000u);
      unsigned int l0 = (d.x & 0xffffu) | (d.y << 16);
      unsigned int l1 = (d.z & 0xffffu) | (d.w << 16);
      *(uint2*)&Shi[row][col] = make_uint2(h0, h1);
      *(uint2*)&Slo[row][col] = make_uint2(l0, l1);
    }
    __syncthreads();   // both waves' plane halves visible
    // WAR safety without a 2nd barrier: staging for t+1 only starts after
    // BOTH waves' flags for t are up (poll), and a wave's flag t is ordered
    // after its MFMA consumed Shi/Slo (acc -> stores -> vmcnt drain -> flag).

    // ---- MFMA: 8x32 tile of state @ W2 slice ------------------------------
    f32x4 a0 = {0,0,0,0}, a1 = {0,0,0,0}, a2 = {0,0,0,0}, a3 = {0,0,0,0};
    #pragma unroll
    for (int ks = 0; ks < 32; ks += 2){
      const int k0 = ks * 32;
      short8 ah0 = *(const short8*)&Shi[r8][k0 + g*8];
      short8 al0 = *(const short8*)&Slo[r8][k0 + g*8];
      short8 ah1 = *(const short8*)&Shi[r8][k0 + 32 + g*8];
      short8 al1 = *(const short8*)&Slo[r8][k0 + 32 + g*8];
      const int c0 = (k0 >> 3) + g, c1 = c0 + 4;
      short8 b0f = *(const short8*)&Wt[nloc][(c0 ^ (nloc & 7))*8];
      short8 b1f = *(const short8*)&Wt[nloc][(c1 ^ (nloc & 7))*8];
      a0 = __builtin_amdgcn_mfma_f32_16x16x32_bf16(ah0, b0f, a0, 0,0,0);
      a1 = __builtin_amdgcn_mfma_f32_16x16x32_bf16(al0, b0f, a1, 0,0,0);
      a2 = __builtin_amdgcn_mfma_f32_16x16x32_bf16(ah1, b1f, a2, 0,0,0);
      a3 = __builtin_amdgcn_mfma_f32_16x16x32_bf16(al1, b1f, a3, 0,0,0);
    }
    f32x4 acc = (a0 + a1) + (a2 + a3);

    // ---- epilogue: rows brow..brow+3 (lanes g<2), col n -------------------
    unsigned int dw[4];
    if (act){
      #pragma unroll
      for (int r = 0; r < 4; ++r){
        const int b = brow + r;
        const float y = hv[r] + tanhf(acc[r] + bias);
        unsigned short yh = f2bf(y);
        unsigned short yl = f2bf(y - bf2f(yh));
        dw[r] = ((unsigned int)yh << 16) | (unsigned int)yl;
        __hip_atomic_store(&wsb[b*1024 + n], dw[r],
                           __ATOMIC_RELAXED, __HIP_MEMORY_SCOPE_AGENT);
      }
    }
    // drain state stores to the coherence point, then publish wave flag
    asm volatile("s_waitcnt vmcnt(0)" ::: "memory");
    if (lane == 0)
      __hip_atomic_store(gflag + (size_t)t*64 + wid, 1u,
                         __ATOMIC_RELAXED, __HIP_MEMORY_SCOPE_AGENT);
    // feat stores AFTER publish: off the critical path
    if (act){
      #pragma unroll
      for (int r = 0; r < 4; ++r)
        feat[(size_t)(brow + r)*Tx*Ux + (size_t)t*Ux + n] = (unsigned short)(dw[r] >> 16);
    }
  }
}

// ---------------------------------------------------------------------------
// proj_out: out[m] = feat[m][:] (bf16) . Wc (fp32) + bc
// ---------------------------------------------------------------------------
__global__ __launch_bounds__(256) void proj_out(
    const unsigned short* __restrict__ feat, const float* __restrict__ Wc,
    const float* __restrict__ bc, float* __restrict__ out)
{
  const int wv = threadIdx.x >> 6, lane = threadIdx.x & 63;
  const int m = blockIdx.x * 4 + wv;
  const unsigned short* fp = &feat[(size_t)m*1024 + lane*16];
  float s = 0.f;
  #pragma unroll
  for (int i = 0; i < 2; ++i){
    uint4 v = *(const uint4*)(fp + i*8);
    float4 w0 = *(const float4*)&Wc[lane*16 + i*8];
    float4 w1 = *(const float4*)&Wc[lane*16 + i*8 + 4];
    unsigned int vv[4] = {v.x, v.y, v.z, v.w};
    s += bf2f((unsigned short)(vv[0] & 0xFFFF))*w0.x + bf2f((unsigned short)(vv[0] >> 16))*w0.y;
    s += bf2f((unsigned short)(vv[1] & 0xFFFF))*w0.z + bf2f((unsigned short)(vv[1] >> 16))*w0.w;
    s += bf2f((unsigned short)(vv[2] & 0xFFFF))*w1.x + bf2f((unsigned short)(vv[2] >> 16))*w1.y;
    s += bf2f((unsigned short)(vv[3] & 0xFFFF))*w1.z + bf2f((unsigned short)(vv[3] >> 16))*w1.w;
  }
  for (int o = 32; o; o >>= 1) s += __shfl_down(s, o);
  if (lane == 0) out[m] = s + bc[0];
}

// ---------------------------------------------------------------------------
extern "C" void kernel_launch(void* const* d_in, const int* in_sizes, int n_in,
                              void* d_out, int out_size, void* d_ws, size_t ws_size,
                              hipStream_t stream)
{
  (void)in_sizes; (void)n_in; (void)out_size; (void)ws_size;
  const float* X  = (const float*)d_in[0];
  const float* W1 = (const float*)d_in[1];
  const float* b1 = (const float*)d_in[2];
  const float* W2 = (const float*)d_in[3];
  const float* b2 = (const float*)d_in[4];
  const float* Wc = (const float*)d_in[5];
  const float* bc = (const float*)d_in[6];
  float* out = (float*)d_out;
  char* ws = (char*)d_ws;

  unsigned short* W1T  = (unsigned short*)(ws + 0);          // 2 MiB
  unsigned short* W2T  = (unsigned short*)(ws + 2097152);    // 2 MiB
  unsigned int*   sP0  = (unsigned int*)  (ws + 4194304);    // 256 KiB packed state
  unsigned int*   sP1  = (unsigned int*)  (ws + 4456448);    // 256 KiB
  unsigned int*   flags= (unsigned int*)  (ws + 4718592);    // 1 MiB (8*512*64*4)
  float* hbuf          = (float*)         (ws + 5767168);    // 128 MiB
  unsigned short* feat = (unsigned short*)(ws + 5767168 + 134217728); // 64 MiB

  // zero state + flags (contiguous 1.5 MiB)
  hipMemsetAsync(sP0, 0, 262144 + 262144 + 1048576, stream);

  prep_kernel<<<dim3(256, 2), 256, 0, stream>>>(W1, W2, W1T, W2T);
  gemm_h<<<dim3(Mx/128, Ux/128), 256, 0, stream>>>(X, W1T, b1, hbuf);

  void* args[] = { (void*)&W2T, (void*)&hbuf, (void*)&b2,
                   (void*)&sP0, (void*)&sP1, (void*)&flags, (void*)&feat };
  hipLaunchCooperativeKernel((void*)rnn_scan, dim3(256), dim3(128), args, 0, stream);

  proj_out<<<Mx/4, 256, 0, stream>>>(feat, Wc, bc, out);
}